// Round 1
// 195.015 us; speedup vs baseline: 1.0178x; 1.0178x over previous
//
#include <hip/hip_runtime.h>
#include <math.h>

// Shapes (fixed by the reference)
#define Bb   16
#define Ss   2048
#define Rr   196
#define Hh   768
#define Mtot (Bb * Rr)      // 3136 rows of img
#define NT   (Hh / 64)      // 12 n-tiles in K1
#define LDA  72             // LDS row stride for f32 fallback path

typedef __attribute__((ext_vector_type(8))) short short8;
typedef __attribute__((ext_vector_type(4))) short short4v;
typedef __attribute__((ext_vector_type(4))) float f32x4;

__device__ inline short f2bf(float f) {
    unsigned u = __builtin_bit_cast(unsigned, f);
    u += 0x7fff + ((u >> 16) & 1);          // round-to-nearest-even
    return (short)(u >> 16);
}

__device__ __forceinline__ void gload_lds16(const void* g, void* l) {
    // 16B direct global->LDS; LDS dest = wave-uniform base + lane*16,
    // global source is per-lane (pre-swizzled there, rule #21).
    __builtin_amdgcn_global_load_lds(
        (const __attribute__((address_space(1))) void*)g,
        (__attribute__((address_space(3))) void*)l, 16, 0, 0);
}

// ---------------------------------------------------------------------------
// K0: fp32 -> bf16 conversion of img (602112 float4) and W_img (147456 float4)
// ---------------------------------------------------------------------------
__global__ __launch_bounds__(256) void k0_cvt(
    const f32x4* __restrict__ a, short4v* __restrict__ da, int na4,
    const f32x4* __restrict__ b, short4v* __restrict__ db)
{
    int gid = blockIdx.x * 256 + threadIdx.x;
    const f32x4* s;
    short4v* d;
    int i;
    if (gid < na4) { s = a; d = da; i = gid; }
    else           { s = b; d = db; i = gid - na4; }
    f32x4 x = s[i];
    short4v o;
    o.x = f2bf(x.x); o.y = f2bf(x.y); o.z = f2bf(x.z); o.w = f2bf(x.w);
    d[i] = o;
}

// ---------------------------------------------------------------------------
// K1 (bf16 path): pre = img (M x K) * W^T (N x K), bf16 MFMA 16x16x32.
// Double-buffered LDS, global_load_lds dwordx4 staging.
// LDS layout is granule-swizzled: physical 16B-granule (r, gp) holds logical
// granule gp ^ (r&7). Staging pre-applies the inverse on the GLOBAL source
// (linear LDS dest, as global_load_lds requires); ds_read applies it again.
// Net effect: ds_read_b128 of a column-slice is bank-conflict-free.
// Fused epilogue: part[nt][m] = sum_{n in 64-tile} tanh(pre[m,n]) * w2[n].
// grid (49, 12), block 256 (4 waves), tile 64x64, BK=64.
// ---------------------------------------------------------------------------
__global__ __launch_bounds__(256) void k1_mfma_bf16(
    const short* __restrict__ A, const short* __restrict__ B,
    const float* __restrict__ w_att, float* __restrict__ part)
{
    const int m0   = blockIdx.x * 64;
    const int n0   = blockIdx.y * 64;
    const int t    = threadIdx.x;
    const int lane = t & 63;
    const int wv   = t >> 6;
    const int wm   = (wv & 1) * 32;
    const int wn   = (wv >> 1) * 32;
    const int col  = lane & 15;
    const int quad = lane >> 4;

    __shared__ short As[2][64 * 64];
    __shared__ short Bs[2][64 * 64];
    __shared__ float red[64][2];

    f32x4 acc[2][2] = {};   // [mi][ni]

    // Staging addressing: thread t covers physical slots t (rows 0..31) and
    // t+256 (rows 32..63). r&7 is identical for both, so one swizzle value.
    const int r0  = t >> 3;                 // 0..31
    const int glt = (t & 7) ^ (r0 & 7);     // logical granule this slot holds
    const short* srcA = A + (size_t)(m0 + r0) * Hh + glt * 8;
    const short* srcB = B + (size_t)(n0 + r0) * Hh + glt * 8;
    const int lo = wv * 512;                // shorts; wave-uniform LDS base

    const auto stage = [&](int buf, int koff) {
        gload_lds16(srcA + koff,           &As[buf][lo]);
        gload_lds16(srcA + koff + 32 * Hh, &As[buf][lo + 2048]);
        gload_lds16(srcB + koff,           &Bs[buf][lo]);
        gload_lds16(srcB + koff + 32 * Hh, &Bs[buf][lo + 2048]);
    };

    // Swizzled read offsets (shorts). Rows wm+col / wm+16+col share (row&7)=col&7.
    const int rowA0 = (wm +      col) * 64;
    const int rowA1 = (wm + 16 + col) * 64;
    const int rowB0 = (wn +      col) * 64;
    const int rowB1 = (wn + 16 + col) * 64;
    const int ph0 = ((quad    ) ^ (col & 7)) * 8;   // kk = 0
    const int ph1 = ((quad + 4) ^ (col & 7)) * 8;   // kk = 32

    stage(0, 0);
    __syncthreads();                        // buf0 staged (vmcnt drained)
#pragma unroll
    for (int kt = 0; kt < NT; ++kt) {
        const int cur = kt & 1;
        if (kt + 1 < NT) stage(cur ^ 1, (kt + 1) * 64);
        const short* as = As[cur];
        const short* bs = Bs[cur];
        short8 a00 = *(const short8*)&as[rowA0 + ph0];
        short8 a10 = *(const short8*)&as[rowA1 + ph0];
        short8 b00 = *(const short8*)&bs[rowB0 + ph0];
        short8 b10 = *(const short8*)&bs[rowB1 + ph0];
        short8 a01 = *(const short8*)&as[rowA0 + ph1];
        short8 a11 = *(const short8*)&as[rowA1 + ph1];
        short8 b01 = *(const short8*)&bs[rowB0 + ph1];
        short8 b11 = *(const short8*)&bs[rowB1 + ph1];
        acc[0][0] = __builtin_amdgcn_mfma_f32_16x16x32_bf16(a00, b00, acc[0][0], 0, 0, 0);
        acc[0][1] = __builtin_amdgcn_mfma_f32_16x16x32_bf16(a00, b10, acc[0][1], 0, 0, 0);
        acc[1][0] = __builtin_amdgcn_mfma_f32_16x16x32_bf16(a10, b00, acc[1][0], 0, 0, 0);
        acc[1][1] = __builtin_amdgcn_mfma_f32_16x16x32_bf16(a10, b10, acc[1][1], 0, 0, 0);
        acc[0][0] = __builtin_amdgcn_mfma_f32_16x16x32_bf16(a01, b01, acc[0][0], 0, 0, 0);
        acc[0][1] = __builtin_amdgcn_mfma_f32_16x16x32_bf16(a01, b11, acc[0][1], 0, 0, 0);
        acc[1][0] = __builtin_amdgcn_mfma_f32_16x16x32_bf16(a11, b01, acc[1][0], 0, 0, 0);
        acc[1][1] = __builtin_amdgcn_mfma_f32_16x16x32_bf16(a11, b11, acc[1][1], 0, 0, 0);
        __syncthreads();   // next buf staged; all reads of cur retired
    }

    // Epilogue: tanh * w2, reduce over this block's 64 n-columns.
    const float* w2 = w_att + Hh;
    float w2v0 = w2[n0 + wn + col];
    float w2v1 = w2[n0 + wn + 16 + col];

#pragma unroll
    for (int mi = 0; mi < 2; ++mi) {
#pragma unroll
        for (int r = 0; r < 4; ++r) {
            float s = tanhf(acc[mi][0][r]) * w2v0 + tanhf(acc[mi][1][r]) * w2v1;
            s += __shfl_xor(s, 1, 64);
            s += __shfl_xor(s, 2, 64);
            s += __shfl_xor(s, 4, 64);
            s += __shfl_xor(s, 8, 64);
            if (col == 0)
                red[wm + mi * 16 + quad * 4 + r][wn >> 5] = s;
        }
    }
    __syncthreads();
    if (t < 64)
        part[blockIdx.y * Mtot + m0 + t] = red[t][0] + red[t][1];
}

// ---------------------------------------------------------------------------
// K1 fallback (f32 inputs, reg staging) — only used if workspace too small.
// Identical to the previously verified FROM_F32 path.
// ---------------------------------------------------------------------------
__global__ __launch_bounds__(256) void k1_mfma_f32(
    const float* __restrict__ A, const float* __restrict__ B,
    const float* __restrict__ w_att, float* __restrict__ part)
{
    const int m0   = blockIdx.x * 64;
    const int n0   = blockIdx.y * 64;
    const int t    = threadIdx.x;
    const int lane = t & 63;
    const int wv   = t >> 6;
    const int wm   = (wv & 1) * 32;
    const int wn   = (wv >> 1) * 32;
    const int col  = lane & 15;
    const int quad = lane >> 4;

    __shared__ short As[64 * LDA];
    __shared__ short Bs[64 * LDA];
    __shared__ float red[64][2];

    f32x4 acc[2][2] = {};

    const int sm = t >> 2;
    const int sq = t & 3;

    for (int k0 = 0; k0 < Hh; k0 += 64) {
        short8 areg[2], breg[2];
#pragma unroll
        for (int j = 0; j < 2; ++j) {
            float4 lo = *(const float4*)&A[(size_t)(m0 + sm) * Hh + k0 + sq * 16 + j * 8];
            float4 hi = *(const float4*)&A[(size_t)(m0 + sm) * Hh + k0 + sq * 16 + j * 8 + 4];
            areg[j][0] = f2bf(lo.x); areg[j][1] = f2bf(lo.y);
            areg[j][2] = f2bf(lo.z); areg[j][3] = f2bf(lo.w);
            areg[j][4] = f2bf(hi.x); areg[j][5] = f2bf(hi.y);
            areg[j][6] = f2bf(hi.z); areg[j][7] = f2bf(hi.w);
            lo = *(const float4*)&B[(size_t)(n0 + sm) * Hh + k0 + sq * 16 + j * 8];
            hi = *(const float4*)&B[(size_t)(n0 + sm) * Hh + k0 + sq * 16 + j * 8 + 4];
            breg[j][0] = f2bf(lo.x); breg[j][1] = f2bf(lo.y);
            breg[j][2] = f2bf(lo.z); breg[j][3] = f2bf(lo.w);
            breg[j][4] = f2bf(hi.x); breg[j][5] = f2bf(hi.y);
            breg[j][6] = f2bf(hi.z); breg[j][7] = f2bf(hi.w);
        }
        __syncthreads();
#pragma unroll
        for (int j = 0; j < 2; ++j) {
            *(short8*)&As[sm * LDA + sq * 16 + j * 8] = areg[j];
            *(short8*)&Bs[sm * LDA + sq * 16 + j * 8] = breg[j];
        }
        __syncthreads();
#pragma unroll
        for (int kk = 0; kk < 64; kk += 32) {
            short8 a0 = *(const short8*)&As[(wm +      col) * LDA + kk + quad * 8];
            short8 a1 = *(const short8*)&As[(wm + 16 + col) * LDA + kk + quad * 8];
            short8 b0 = *(const short8*)&Bs[(wn +      col) * LDA + kk + quad * 8];
            short8 b1 = *(const short8*)&Bs[(wn + 16 + col) * LDA + kk + quad * 8];
            acc[0][0] = __builtin_amdgcn_mfma_f32_16x16x32_bf16(a0, b0, acc[0][0], 0, 0, 0);
            acc[0][1] = __builtin_amdgcn_mfma_f32_16x16x32_bf16(a0, b1, acc[0][1], 0, 0, 0);
            acc[1][0] = __builtin_amdgcn_mfma_f32_16x16x32_bf16(a1, b0, acc[1][0], 0, 0, 0);
            acc[1][1] = __builtin_amdgcn_mfma_f32_16x16x32_bf16(a1, b1, acc[1][1], 0, 0, 0);
        }
    }

    const float* w2 = w_att + Hh;
    float w2v0 = w2[n0 + wn + col];
    float w2v1 = w2[n0 + wn + 16 + col];

#pragma unroll
    for (int mi = 0; mi < 2; ++mi) {
#pragma unroll
        for (int r = 0; r < 4; ++r) {
            float s = tanhf(acc[mi][0][r]) * w2v0 + tanhf(acc[mi][1][r]) * w2v1;
            s += __shfl_xor(s, 1, 64);
            s += __shfl_xor(s, 2, 64);
            s += __shfl_xor(s, 4, 64);
            s += __shfl_xor(s, 8, 64);
            if (col == 0)
                red[wm + mi * 16 + quad * 4 + r][wn >> 5] = s;
        }
    }
    __syncthreads();
    if (t < 64)
        part[blockIdx.y * Mtot + m0 + t] = red[t][0] + red[t][1];
}

// ---------------------------------------------------------------------------
// K2: per batch b: scores[r] = sum_nt part[nt][b*Rr+r]; p = softmax(scores);
//     v[b,h] = sum_r p[r] * img[b,r,h].   grid (16, 12).
// Wave-level shuffle reductions: 5 barriers total (was 17).
// ---------------------------------------------------------------------------
__global__ __launch_bounds__(256) void k2_softmax_v(
    const float* __restrict__ part,
    const float* __restrict__ img,
    float* __restrict__ v)
{
    const int b    = blockIdx.x;
    const int t    = threadIdx.x;
    const int lane = t & 63;
    const int wv   = t >> 6;

    __shared__ float p[Rr];
    __shared__ float wred[4];
    __shared__ float a2[4][65];

    float s = 0.f;
    if (t < Rr) {
#pragma unroll
        for (int nt = 0; nt < NT; ++nt) s += part[nt * Mtot + b * Rr + t];
    }

    // max over 196 scores: wave shuffle reduce, then 4-entry combine
    float m = (t < Rr) ? s : -INFINITY;
#pragma unroll
    for (int off = 1; off < 64; off <<= 1) m = fmaxf(m, __shfl_xor(m, off, 64));
    if (lane == 0) wred[wv] = m;
    __syncthreads();
    const float mx = fmaxf(fmaxf(wred[0], wred[1]), fmaxf(wred[2], wred[3]));

    float e = (t < Rr) ? expf(s - mx) : 0.f;
    float sum = e;
#pragma unroll
    for (int off = 1; off < 64; off <<= 1) sum += __shfl_xor(sum, off, 64);
    __syncthreads();                 // all mx reads done before wred reuse
    if (lane == 0) wred[wv] = sum;
    __syncthreads();
    const float inv = 1.f / (wred[0] + wred[1] + wred[2] + wred[3]);
    if (t < Rr) p[t] = e * inv;
    __syncthreads();

    // weighted sum over r, split in 4 groups of 49
    const int h  = blockIdx.y * 64 + (t & 63);
    const int rg = t >> 6;
    const float* imgb = img + (size_t)b * Rr * Hh + h;
    float acc = 0.f;
#pragma unroll 7
    for (int r = rg * 49; r < rg * 49 + 49; ++r)
        acc = fmaf(p[r], imgb[(size_t)r * Hh], acc);
    a2[rg][t & 63] = acc;
    __syncthreads();
    if (t < 64)
        v[b * Hh + blockIdx.y * 64 + t] = a2[0][t] + a2[1][t] + a2[2][t] + a2[3][t];
}

// ---------------------------------------------------------------------------
// K3: out[b,s,:] = v[b,:]  — 100 MB of nontemporal vector stores.
// ---------------------------------------------------------------------------
__global__ __launch_bounds__(256) void k3_bcast(
    const f32x4* __restrict__ v4,
    f32x4* __restrict__ out)
{
    const int gid   = blockIdx.x * 256 + threadIdx.x;   // < 6291456
    const int per_b = Ss * (Hh / 4);                    // 393216 f32x4 per batch
    const int b     = gid / per_b;
    const int h4    = gid % (Hh / 4);                   // 0..191
    f32x4 val = v4[b * (Hh / 4) + h4];
    __builtin_nontemporal_store(val, &out[gid]);
}

// ---------------------------------------------------------------------------
extern "C" void kernel_launch(void* const* d_in, const int* in_sizes, int n_in,
                              void* d_out, int out_size, void* d_ws, size_t ws_size,
                              hipStream_t stream)
{
    // Input order: text_features, img_features, W_text, b_text, W_img, w_att, b_att
    const float* img   = (const float*)d_in[1];
    const float* W_img = (const float*)d_in[4];
    const float* w_att = (const float*)d_in[5];
    // text_features / W_text / b_text / b_att are mathematically dead:
    // softmax over r is invariant to the per-(b,s) text score and to b_att.

    float* part = (float*)d_ws;                  // NT*Mtot floats   = 150528 B
    float* v    = part + NT * Mtot;              // Bb*Hh floats     =  49152 B
    size_t off  = ((size_t)(NT * Mtot + Bb * Hh) * 4 + 15) & ~(size_t)15;
    short* imgbf = (short*)((char*)d_ws + off);                  // 4816896 B
    short* Wbf   = imgbf + (size_t)Mtot * Hh;                    // 1179648 B
    const size_t need = off + ((size_t)Mtot * Hh + (size_t)Hh * Hh) * 2;

    float* out = (float*)d_out;
    const bool usebf = (ws_size >= need);        // constant across calls -> graph-safe

    if (usebf) {
        const int na4 = (Mtot * Hh) / 4;         // 602112
        const int nb4 = (Hh * Hh) / 4;           // 147456
        k0_cvt<<<(na4 + nb4) / 256, 256, 0, stream>>>(
            (const f32x4*)img, (short4v*)imgbf, na4,
            (const f32x4*)W_img, (short4v*)Wbf);
        k1_mfma_bf16<<<dim3(Mtot / 64, NT), 256, 0, stream>>>(imgbf, Wbf, w_att, part);
    } else {
        k1_mfma_f32<<<dim3(Mtot / 64, NT), 256, 0, stream>>>(img, W_img, w_att, part);
    }

    k2_softmax_v<<<dim3(Bb, NT), 256, 0, stream>>>(part, img, v);

    const int total4 = Bb * Ss * (Hh / 4);       // 6291456
    k3_bcast<<<total4 / 256, 256, 0, stream>>>((const f32x4*)v, (f32x4*)out);
}

// Round 2
// 194.606 us; speedup vs baseline: 1.0199x; 1.0021x over previous
//
#include <hip/hip_runtime.h>
#include <math.h>

// Shapes (fixed by the reference)
#define Bb   16
#define Ss   2048
#define Rr   196
#define Hh   768
#define Mtot (Bb * Rr)      // 3136 rows of img
#define NT   (Hh / 64)      // 12 n-tiles in K1
#define LDA  72             // LDS row stride for f32 fallback path

typedef __attribute__((ext_vector_type(8))) short short8;
typedef __attribute__((ext_vector_type(4))) short short4v;
typedef __attribute__((ext_vector_type(4))) float f32x4;

__device__ inline short f2bf(float f) {
    unsigned u = __builtin_bit_cast(unsigned, f);
    u += 0x7fff + ((u >> 16) & 1);          // round-to-nearest-even
    return (short)(u >> 16);
}

__device__ __forceinline__ void gload_lds16(const void* g, void* l) {
    // 16B direct global->LDS; LDS dest = wave-uniform base + lane*16,
    // global source is per-lane (pre-swizzled there, rule #21).
    __builtin_amdgcn_global_load_lds(
        (const __attribute__((address_space(1))) void*)g,
        (__attribute__((address_space(3))) void*)l, 16, 0, 0);
}

// ---------------------------------------------------------------------------
// K0: fp32 -> bf16 conversion of img (602112 float4) and W_img (147456 float4)
// ---------------------------------------------------------------------------
__global__ __launch_bounds__(256) void k0_cvt(
    const f32x4* __restrict__ a, short4v* __restrict__ da, int na4,
    const f32x4* __restrict__ b, short4v* __restrict__ db)
{
    int gid = blockIdx.x * 256 + threadIdx.x;
    const f32x4* s;
    short4v* d;
    int i;
    if (gid < na4) { s = a; d = da; i = gid; }
    else           { s = b; d = db; i = gid - na4; }
    f32x4 x = s[i];
    short4v o;
    o.x = f2bf(x.x); o.y = f2bf(x.y); o.z = f2bf(x.z); o.w = f2bf(x.w);
    d[i] = o;
}

// ---------------------------------------------------------------------------
// K1 (bf16 path): pre = img (M x K) * W^T (N x K), bf16 MFMA 16x16x32.
// Double-buffered LDS, global_load_lds dwordx4 staging, XOR-swizzled layout
// (linear LDS dest + inverse-swizzled global source + swizzled ds_read).
// Fused epilogue: part[nt][m] = sum_{n in 64-tile} tanh(pre[m,n]) * w2[n].
// grid (49, 12), block 256 (4 waves), tile 64x64, BK=64.
// ---------------------------------------------------------------------------
__global__ __launch_bounds__(256) void k1_mfma_bf16(
    const short* __restrict__ A, const short* __restrict__ B,
    const float* __restrict__ w_att, float* __restrict__ part)
{
    const int m0   = blockIdx.x * 64;
    const int n0   = blockIdx.y * 64;
    const int t    = threadIdx.x;
    const int lane = t & 63;
    const int wv   = t >> 6;
    const int wm   = (wv & 1) * 32;
    const int wn   = (wv >> 1) * 32;
    const int col  = lane & 15;
    const int quad = lane >> 4;

    __shared__ short As[2][64 * 64];
    __shared__ short Bs[2][64 * 64];
    __shared__ float red[64][2];

    f32x4 acc[2][2] = {};   // [mi][ni]

    // Staging addressing: thread t covers physical slots t (rows 0..31) and
    // t+256 (rows 32..63). r&7 is identical for both, so one swizzle value.
    const int r0  = t >> 3;                 // 0..31
    const int glt = (t & 7) ^ (r0 & 7);     // logical granule this slot holds
    const short* srcA = A + (size_t)(m0 + r0) * Hh + glt * 8;
    const short* srcB = B + (size_t)(n0 + r0) * Hh + glt * 8;
    const int lo = wv * 512;                // shorts; wave-uniform LDS base

    const auto stage = [&](int buf, int koff) {
        gload_lds16(srcA + koff,           &As[buf][lo]);
        gload_lds16(srcA + koff + 32 * Hh, &As[buf][lo + 2048]);
        gload_lds16(srcB + koff,           &Bs[buf][lo]);
        gload_lds16(srcB + koff + 32 * Hh, &Bs[buf][lo + 2048]);
    };

    // Swizzled read offsets (shorts). Rows wm+col / wm+16+col share (row&7)=col&7.
    const int rowA0 = (wm +      col) * 64;
    const int rowA1 = (wm + 16 + col) * 64;
    const int rowB0 = (wn +      col) * 64;
    const int rowB1 = (wn + 16 + col) * 64;
    const int ph0 = ((quad    ) ^ (col & 7)) * 8;   // kk = 0
    const int ph1 = ((quad + 4) ^ (col & 7)) * 8;   // kk = 32

    stage(0, 0);
    __syncthreads();                        // buf0 staged (vmcnt drained)
#pragma unroll
    for (int kt = 0; kt < NT; ++kt) {
        const int cur = kt & 1;
        if (kt + 1 < NT) stage(cur ^ 1, (kt + 1) * 64);
        const short* as = As[cur];
        const short* bs = Bs[cur];
        short8 a00 = *(const short8*)&as[rowA0 + ph0];
        short8 a10 = *(const short8*)&as[rowA1 + ph0];
        short8 b00 = *(const short8*)&bs[rowB0 + ph0];
        short8 b10 = *(const short8*)&bs[rowB1 + ph0];
        short8 a01 = *(const short8*)&as[rowA0 + ph1];
        short8 a11 = *(const short8*)&as[rowA1 + ph1];
        short8 b01 = *(const short8*)&bs[rowB0 + ph1];
        short8 b11 = *(const short8*)&bs[rowB1 + ph1];
        acc[0][0] = __builtin_amdgcn_mfma_f32_16x16x32_bf16(a00, b00, acc[0][0], 0, 0, 0);
        acc[0][1] = __builtin_amdgcn_mfma_f32_16x16x32_bf16(a00, b10, acc[0][1], 0, 0, 0);
        acc[1][0] = __builtin_amdgcn_mfma_f32_16x16x32_bf16(a10, b00, acc[1][0], 0, 0, 0);
        acc[1][1] = __builtin_amdgcn_mfma_f32_16x16x32_bf16(a10, b10, acc[1][1], 0, 0, 0);
        acc[0][0] = __builtin_amdgcn_mfma_f32_16x16x32_bf16(a01, b01, acc[0][0], 0, 0, 0);
        acc[0][1] = __builtin_amdgcn_mfma_f32_16x16x32_bf16(a01, b11, acc[0][1], 0, 0, 0);
        acc[1][0] = __builtin_amdgcn_mfma_f32_16x16x32_bf16(a11, b01, acc[1][0], 0, 0, 0);
        acc[1][1] = __builtin_amdgcn_mfma_f32_16x16x32_bf16(a11, b11, acc[1][1], 0, 0, 0);
        __syncthreads();   // next buf staged; all reads of cur retired
    }

    // Epilogue: tanh * w2, reduce over this block's 64 n-columns.
    const float* w2 = w_att + Hh;
    float w2v0 = w2[n0 + wn + col];
    float w2v1 = w2[n0 + wn + 16 + col];

#pragma unroll
    for (int mi = 0; mi < 2; ++mi) {
#pragma unroll
        for (int r = 0; r < 4; ++r) {
            float s = tanhf(acc[mi][0][r]) * w2v0 + tanhf(acc[mi][1][r]) * w2v1;
            s += __shfl_xor(s, 1, 64);
            s += __shfl_xor(s, 2, 64);
            s += __shfl_xor(s, 4, 64);
            s += __shfl_xor(s, 8, 64);
            if (col == 0)
                red[wm + mi * 16 + quad * 4 + r][wn >> 5] = s;
        }
    }
    __syncthreads();
    if (t < 64)
        part[blockIdx.y * Mtot + m0 + t] = red[t][0] + red[t][1];
}

// ---------------------------------------------------------------------------
// K1 fallback (f32 inputs, reg staging) — only used if workspace too small.
// ---------------------------------------------------------------------------
__global__ __launch_bounds__(256) void k1_mfma_f32(
    const float* __restrict__ A, const float* __restrict__ B,
    const float* __restrict__ w_att, float* __restrict__ part)
{
    const int m0   = blockIdx.x * 64;
    const int n0   = blockIdx.y * 64;
    const int t    = threadIdx.x;
    const int lane = t & 63;
    const int wv   = t >> 6;
    const int wm   = (wv & 1) * 32;
    const int wn   = (wv >> 1) * 32;
    const int col  = lane & 15;
    const int quad = lane >> 4;

    __shared__ short As[64 * LDA];
    __shared__ short Bs[64 * LDA];
    __shared__ float red[64][2];

    f32x4 acc[2][2] = {};

    const int sm = t >> 2;
    const int sq = t & 3;

    for (int k0 = 0; k0 < Hh; k0 += 64) {
        short8 areg[2], breg[2];
#pragma unroll
        for (int j = 0; j < 2; ++j) {
            float4 lo = *(const float4*)&A[(size_t)(m0 + sm) * Hh + k0 + sq * 16 + j * 8];
            float4 hi = *(const float4*)&A[(size_t)(m0 + sm) * Hh + k0 + sq * 16 + j * 8 + 4];
            areg[j][0] = f2bf(lo.x); areg[j][1] = f2bf(lo.y);
            areg[j][2] = f2bf(lo.z); areg[j][3] = f2bf(lo.w);
            areg[j][4] = f2bf(hi.x); areg[j][5] = f2bf(hi.y);
            areg[j][6] = f2bf(hi.z); areg[j][7] = f2bf(hi.w);
            lo = *(const float4*)&B[(size_t)(n0 + sm) * Hh + k0 + sq * 16 + j * 8];
            hi = *(const float4*)&B[(size_t)(n0 + sm) * Hh + k0 + sq * 16 + j * 8 + 4];
            breg[j][0] = f2bf(lo.x); breg[j][1] = f2bf(lo.y);
            breg[j][2] = f2bf(lo.z); breg[j][3] = f2bf(lo.w);
            breg[j][4] = f2bf(hi.x); breg[j][5] = f2bf(hi.y);
            breg[j][6] = f2bf(hi.z); breg[j][7] = f2bf(hi.w);
        }
        __syncthreads();
#pragma unroll
        for (int j = 0; j < 2; ++j) {
            *(short8*)&As[sm * LDA + sq * 16 + j * 8] = areg[j];
            *(short8*)&Bs[sm * LDA + sq * 16 + j * 8] = breg[j];
        }
        __syncthreads();
#pragma unroll
        for (int kk = 0; kk < 64; kk += 32) {
            short8 a0 = *(const short8*)&As[(wm +      col) * LDA + kk + quad * 8];
            short8 a1 = *(const short8*)&As[(wm + 16 + col) * LDA + kk + quad * 8];
            short8 b0 = *(const short8*)&Bs[(wn +      col) * LDA + kk + quad * 8];
            short8 b1 = *(const short8*)&Bs[(wn + 16 + col) * LDA + kk + quad * 8];
            acc[0][0] = __builtin_amdgcn_mfma_f32_16x16x32_bf16(a0, b0, acc[0][0], 0, 0, 0);
            acc[0][1] = __builtin_amdgcn_mfma_f32_16x16x32_bf16(a0, b1, acc[0][1], 0, 0, 0);
            acc[1][0] = __builtin_amdgcn_mfma_f32_16x16x32_bf16(a1, b0, acc[1][0], 0, 0, 0);
            acc[1][1] = __builtin_amdgcn_mfma_f32_16x16x32_bf16(a1, b1, acc[1][1], 0, 0, 0);
        }
    }

    const float* w2 = w_att + Hh;
    float w2v0 = w2[n0 + wn + col];
    float w2v1 = w2[n0 + wn + 16 + col];

#pragma unroll
    for (int mi = 0; mi < 2; ++mi) {
#pragma unroll
        for (int r = 0; r < 4; ++r) {
            float s = tanhf(acc[mi][0][r]) * w2v0 + tanhf(acc[mi][1][r]) * w2v1;
            s += __shfl_xor(s, 1, 64);
            s += __shfl_xor(s, 2, 64);
            s += __shfl_xor(s, 4, 64);
            s += __shfl_xor(s, 8, 64);
            if (col == 0)
                red[wm + mi * 16 + quad * 4 + r][wn >> 5] = s;
        }
    }
    __syncthreads();
    if (t < 64)
        part[blockIdx.y * Mtot + m0 + t] = red[t][0] + red[t][1];
}

// ---------------------------------------------------------------------------
// K2 (fused with old K3): per batch b:
//   scores[r] = sum_nt part[nt][b*Rr+r]; p = softmax(scores);
//   vchunk[h'] = sum_r p[r] * img[b,r,h0+h']   (h' in 0..63)
//   out[b, s, h0:h0+64] = vchunk  for all s    (nontemporal broadcast)
// grid (16, 12). Eliminates the separate 24576-block broadcast kernel and
// the v round-trip through global memory.
// ---------------------------------------------------------------------------
__global__ __launch_bounds__(256) void k2_softmax_bcast(
    const float* __restrict__ part,
    const float* __restrict__ img,
    float* __restrict__ out)
{
    const int b    = blockIdx.x;
    const int t    = threadIdx.x;
    const int lane = t & 63;
    const int wv   = t >> 6;

    __shared__ float p[Rr];
    __shared__ float wred[4];
    __shared__ float a2[4][65];
    __shared__ float vsh[64];

    float s = 0.f;
    if (t < Rr) {
#pragma unroll
        for (int nt = 0; nt < NT; ++nt) s += part[nt * Mtot + b * Rr + t];
    }

    // max over 196 scores: wave shuffle reduce, then 4-entry combine
    float m = (t < Rr) ? s : -INFINITY;
#pragma unroll
    for (int off = 1; off < 64; off <<= 1) m = fmaxf(m, __shfl_xor(m, off, 64));
    if (lane == 0) wred[wv] = m;
    __syncthreads();
    const float mx = fmaxf(fmaxf(wred[0], wred[1]), fmaxf(wred[2], wred[3]));

    float e = (t < Rr) ? expf(s - mx) : 0.f;
    float sum = e;
#pragma unroll
    for (int off = 1; off < 64; off <<= 1) sum += __shfl_xor(sum, off, 64);
    __syncthreads();                 // all mx reads done before wred reuse
    if (lane == 0) wred[wv] = sum;
    __syncthreads();
    const float inv = 1.f / (wred[0] + wred[1] + wred[2] + wred[3]);
    if (t < Rr) p[t] = e * inv;
    __syncthreads();

    // weighted sum over r, split in 4 groups of 49
    const int h0 = blockIdx.y * 64;
    const int rg = t >> 6;
    const float* imgb = img + (size_t)b * Rr * Hh + h0 + (t & 63);
    float acc = 0.f;
#pragma unroll 7
    for (int r = rg * 49; r < rg * 49 + 49; ++r)
        acc = fmaf(p[r], imgb[(size_t)r * Hh], acc);
    a2[rg][t & 63] = acc;
    __syncthreads();
    if (t < 64) vsh[t] = a2[0][t] + a2[1][t] + a2[2][t] + a2[3][t];
    __syncthreads();

    // Broadcast: out[b, s, h0:h0+64] = vsh for every s.
    // Thread (s16, h4): s16 = t>>4 (0..15), h4 = t&15; each 16-lane group
    // writes one row's 256 contiguous bytes (full lines, no RMW).
    const int h4 = t & 15;
    const int s0 = t >> 4;
    const f32x4 val = *(const f32x4*)&vsh[h4 * 4];
    f32x4* op = (f32x4*)(out + (size_t)b * Ss * Hh + (size_t)s0 * Hh + h0) + h4;
#pragma unroll 8
    for (int k = 0; k < Ss / 16; ++k) {
        __builtin_nontemporal_store(val, op);
        op += 16 * (Hh / 4);
    }
}

// ---------------------------------------------------------------------------
extern "C" void kernel_launch(void* const* d_in, const int* in_sizes, int n_in,
                              void* d_out, int out_size, void* d_ws, size_t ws_size,
                              hipStream_t stream)
{
    // Input order: text_features, img_features, W_text, b_text, W_img, w_att, b_att
    const float* img   = (const float*)d_in[1];
    const float* W_img = (const float*)d_in[4];
    const float* w_att = (const float*)d_in[5];
    // text_features / W_text / b_text / b_att are mathematically dead:
    // softmax over r is invariant to the per-(b,s) text score and to b_att.

    float* part = (float*)d_ws;                  // NT*Mtot floats   = 150528 B
    size_t off  = ((size_t)(NT * Mtot + Bb * Hh) * 4 + 15) & ~(size_t)15;
    short* imgbf = (short*)((char*)d_ws + off);                  // 4816896 B
    short* Wbf   = imgbf + (size_t)Mtot * Hh;                    // 1179648 B
    const size_t need = off + ((size_t)Mtot * Hh + (size_t)Hh * Hh) * 2;

    float* out = (float*)d_out;
    const bool usebf = (ws_size >= need);        // constant across calls -> graph-safe

    if (usebf) {
        const int na4 = (Mtot * Hh) / 4;         // 602112
        const int nb4 = (Hh * Hh) / 4;           // 147456
        k0_cvt<<<(na4 + nb4) / 256, 256, 0, stream>>>(
            (const f32x4*)img, (short4v*)imgbf, na4,
            (const f32x4*)W_img, (short4v*)Wbf);
        k1_mfma_bf16<<<dim3(Mtot / 64, NT), 256, 0, stream>>>(imgbf, Wbf, w_att, part);
    } else {
        k1_mfma_f32<<<dim3(Mtot / 64, NT), 256, 0, stream>>>(img, W_img, w_att, part);
    }

    k2_softmax_bcast<<<dim3(Bb, NT), 256, 0, stream>>>(part, img, out);
}

// Round 3
// 194.594 us; speedup vs baseline: 1.0200x; 1.0001x over previous
//
#include <hip/hip_runtime.h>
#include <math.h>

// Shapes (fixed by the reference)
#define Bb   16
#define Ss   2048
#define Rr   196
#define Hh   768
#define Mtot (Bb * Rr)      // 3136 rows of img
#define NT   (Hh / 64)      // 12 n-tiles (f32 fallback path)
#define NT2  (Hh / 128)     // 6 n-tiles (bf16 path)
#define LDA  72             // LDS row stride for f32 fallback path

typedef __attribute__((ext_vector_type(8))) short short8;
typedef __attribute__((ext_vector_type(4))) short short4v;
typedef __attribute__((ext_vector_type(4))) float f32x4;

__device__ inline short f2bf(float f) {
    unsigned u = __builtin_bit_cast(unsigned, f);
    u += 0x7fff + ((u >> 16) & 1);          // round-to-nearest-even
    return (short)(u >> 16);
}

__device__ __forceinline__ float tanh_fast(float x) {
    // tanh(x) = 1 - 2/(exp(2x)+1). Exact limits at +-inf; ~1e-6 rel error,
    // far below the bf16-MFMA error floor. v_exp_f32 + v_rcp_f32.
    float e = __expf(2.0f * x);
    return fmaf(-2.0f, __builtin_amdgcn_rcpf(e + 1.0f), 1.0f);
}

__device__ __forceinline__ void gload_lds16(const void* g, void* l) {
    // 16B direct global->LDS; LDS dest = wave-uniform base + lane*16,
    // global source is per-lane (pre-swizzled there, rule #21).
    __builtin_amdgcn_global_load_lds(
        (const __attribute__((address_space(1))) void*)g,
        (__attribute__((address_space(3))) void*)l, 16, 0, 0);
}

// ---------------------------------------------------------------------------
// K0: fp32 -> bf16 conversion of img (602112 float4) and W_img (147456 float4)
// ---------------------------------------------------------------------------
__global__ __launch_bounds__(256) void k0_cvt(
    const f32x4* __restrict__ a, short4v* __restrict__ da, int na4,
    const f32x4* __restrict__ b, short4v* __restrict__ db)
{
    int gid = blockIdx.x * 256 + threadIdx.x;
    const f32x4* s;
    short4v* d;
    int i;
    if (gid < na4) { s = a; d = da; i = gid; }
    else           { s = b; d = db; i = gid - na4; }
    f32x4 x = s[i];
    short4v o;
    o.x = f2bf(x.x); o.y = f2bf(x.y); o.z = f2bf(x.z); o.w = f2bf(x.w);
    d[i] = o;
}

// ---------------------------------------------------------------------------
// K1 (bf16 path): pre = img (M x K) * W^T (N x K), bf16 MFMA 16x16x32.
// Tile 64(M) x 128(N), 4 waves in 2x2, wave tile 32x64 (acc 2x4).
// Per k-half a wave reads 6 ds_read_b128 and issues 8 MFMA (ratio 1.33 vs
// the previous 1.0) -> 25% less LDS-read traffic on the critical path.
// Double-buffered LDS, global_load_lds dwordx4 staging, XOR-swizzled layout
// (linear LDS dest + inverse-swizzled global source + swizzled ds_read).
// Fused epilogue: part[nt][m] = sum_{n in 128-tile} tanh(pre[m,n]) * w2[n].
// grid (49, 6), block 256.
// ---------------------------------------------------------------------------
__global__ __launch_bounds__(256) void k1_mfma_bf16(
    const short* __restrict__ A, const short* __restrict__ B,
    const float* __restrict__ w_att, float* __restrict__ part)
{
    const int m0   = blockIdx.x * 64;
    const int n0   = blockIdx.y * 128;
    const int t    = threadIdx.x;
    const int lane = t & 63;
    const int wv   = t >> 6;
    const int wm   = (wv & 1) * 32;     // wave M offset: 0/32
    const int wn   = (wv >> 1) * 64;    // wave N offset: 0/64
    const int col  = lane & 15;
    const int quad = lane >> 4;

    __shared__ short As[2][64 * 64];    // 8 KB per buffer
    __shared__ short Bs[2][128 * 64];   // 16 KB per buffer
    __shared__ float red[64][2];

    f32x4 acc[2][4] = {};   // [mi][nj]

    // Staging: thread t covers physical rows r0 + 32j (swizzle term r&7 is
    // invariant in j since 32 % 8 == 0 -> one glt per thread).
    const int r0  = t >> 3;                 // 0..31
    const int glt = (t & 7) ^ (r0 & 7);     // logical granule this slot holds
    const short* srcA = A + (size_t)(m0 + r0) * Hh + glt * 8;
    const short* srcB = B + (size_t)(n0 + r0) * Hh + glt * 8;
    const int lo = wv * 512;                // shorts; wave-uniform LDS base

    const auto stage = [&](int buf, int koff) {
#pragma unroll
        for (int j = 0; j < 2; ++j)         // A: 64 rows = 2 x 4KB chunks
            gload_lds16(srcA + koff + j * 32 * Hh, &As[buf][lo + j * 2048]);
#pragma unroll
        for (int j = 0; j < 4; ++j)         // B: 128 rows = 4 x 4KB chunks
            gload_lds16(srcB + koff + j * 32 * Hh, &Bs[buf][lo + j * 2048]);
    };

    // Swizzled read offsets (shorts). All frag rows share (row&7) == (col&7).
    int rowA[2], rowB[4];
#pragma unroll
    for (int i = 0; i < 2; ++i) rowA[i] = (wm + 16 * i + col) * 64;
#pragma unroll
    for (int j = 0; j < 4; ++j) rowB[j] = (wn + 16 * j + col) * 64;
    const int ph0 = ((quad    ) ^ (col & 7)) * 8;   // kk = 0
    const int ph1 = ((quad + 4) ^ (col & 7)) * 8;   // kk = 32

    stage(0, 0);
    __syncthreads();                        // buf0 staged (vmcnt drained)
#pragma unroll
    for (int kt = 0; kt < NT; ++kt) {       // 12 K-steps of 64
        const int cur = kt & 1;
        if (kt + 1 < NT) stage(cur ^ 1, (kt + 1) * 64);
        const short* as = As[cur];
        const short* bs = Bs[cur];
#pragma unroll
        for (int h = 0; h < 2; ++h) {
            const int ph = h ? ph1 : ph0;
            short8 av[2], bv[4];
#pragma unroll
            for (int i = 0; i < 2; ++i) av[i] = *(const short8*)&as[rowA[i] + ph];
#pragma unroll
            for (int j = 0; j < 4; ++j) bv[j] = *(const short8*)&bs[rowB[j] + ph];
#pragma unroll
            for (int i = 0; i < 2; ++i)
#pragma unroll
                for (int j = 0; j < 4; ++j)
                    acc[i][j] = __builtin_amdgcn_mfma_f32_16x16x32_bf16(
                        av[i], bv[j], acc[i][j], 0, 0, 0);
        }
        __syncthreads();   // next buf staged; all reads of cur retired
    }

    // Epilogue: tanh * w2, reduce over this block's 128 n-columns.
    const float* w2 = w_att + Hh;
    float w2v[4];
#pragma unroll
    for (int j = 0; j < 4; ++j) w2v[j] = w2[n0 + wn + 16 * j + col];

#pragma unroll
    for (int mi = 0; mi < 2; ++mi) {
#pragma unroll
        for (int r = 0; r < 4; ++r) {
            float s = 0.f;
#pragma unroll
            for (int j = 0; j < 4; ++j)
                s += tanh_fast(acc[mi][j][r]) * w2v[j];
            s += __shfl_xor(s, 1, 64);
            s += __shfl_xor(s, 2, 64);
            s += __shfl_xor(s, 4, 64);
            s += __shfl_xor(s, 8, 64);
            if (col == 0)
                red[wm + mi * 16 + quad * 4 + r][wn >> 6] = s;
        }
    }
    __syncthreads();
    if (t < 64)
        part[blockIdx.y * Mtot + m0 + t] = red[t][0] + red[t][1];
}

// ---------------------------------------------------------------------------
// K1 fallback (f32 inputs, reg staging) — only used if workspace too small.
// Writes 12 part segments (grid (49,12)).
// ---------------------------------------------------------------------------
__global__ __launch_bounds__(256) void k1_mfma_f32(
    const float* __restrict__ A, const float* __restrict__ B,
    const float* __restrict__ w_att, float* __restrict__ part)
{
    const int m0   = blockIdx.x * 64;
    const int n0   = blockIdx.y * 64;
    const int t    = threadIdx.x;
    const int lane = t & 63;
    const int wv   = t >> 6;
    const int wm   = (wv & 1) * 32;
    const int wn   = (wv >> 1) * 32;
    const int col  = lane & 15;
    const int quad = lane >> 4;

    __shared__ short As[64 * LDA];
    __shared__ short Bs[64 * LDA];
    __shared__ float red[64][2];

    f32x4 acc[2][2] = {};

    const int sm = t >> 2;
    const int sq = t & 3;

    for (int k0 = 0; k0 < Hh; k0 += 64) {
        short8 areg[2], breg[2];
#pragma unroll
        for (int j = 0; j < 2; ++j) {
            float4 lo = *(const float4*)&A[(size_t)(m0 + sm) * Hh + k0 + sq * 16 + j * 8];
            float4 hi = *(const float4*)&A[(size_t)(m0 + sm) * Hh + k0 + sq * 16 + j * 8 + 4];
            areg[j][0] = f2bf(lo.x); areg[j][1] = f2bf(lo.y);
            areg[j][2] = f2bf(lo.z); areg[j][3] = f2bf(lo.w);
            areg[j][4] = f2bf(hi.x); areg[j][5] = f2bf(hi.y);
            areg[j][6] = f2bf(hi.z); areg[j][7] = f2bf(hi.w);
            lo = *(const float4*)&B[(size_t)(n0 + sm) * Hh + k0 + sq * 16 + j * 8];
            hi = *(const float4*)&B[(size_t)(n0 + sm) * Hh + k0 + sq * 16 + j * 8 + 4];
            breg[j][0] = f2bf(lo.x); breg[j][1] = f2bf(lo.y);
            breg[j][2] = f2bf(lo.z); breg[j][3] = f2bf(lo.w);
            breg[j][4] = f2bf(hi.x); breg[j][5] = f2bf(hi.y);
            breg[j][6] = f2bf(hi.z); breg[j][7] = f2bf(hi.w);
        }
        __syncthreads();
#pragma unroll
        for (int j = 0; j < 2; ++j) {
            *(short8*)&As[sm * LDA + sq * 16 + j * 8] = areg[j];
            *(short8*)&Bs[sm * LDA + sq * 16 + j * 8] = breg[j];
        }
        __syncthreads();
#pragma unroll
        for (int kk = 0; kk < 64; kk += 32) {
            short8 a0 = *(const short8*)&As[(wm +      col) * LDA + kk + quad * 8];
            short8 a1 = *(const short8*)&As[(wm + 16 + col) * LDA + kk + quad * 8];
            short8 b0 = *(const short8*)&Bs[(wn +      col) * LDA + kk + quad * 8];
            short8 b1 = *(const short8*)&Bs[(wn + 16 + col) * LDA + kk + quad * 8];
            acc[0][0] = __builtin_amdgcn_mfma_f32_16x16x32_bf16(a0, b0, acc[0][0], 0, 0, 0);
            acc[0][1] = __builtin_amdgcn_mfma_f32_16x16x32_bf16(a0, b1, acc[0][1], 0, 0, 0);
            acc[1][0] = __builtin_amdgcn_mfma_f32_16x16x32_bf16(a1, b0, acc[1][0], 0, 0, 0);
            acc[1][1] = __builtin_amdgcn_mfma_f32_16x16x32_bf16(a1, b1, acc[1][1], 0, 0, 0);
        }
    }

    const float* w2 = w_att + Hh;
    float w2v0 = w2[n0 + wn + col];
    float w2v1 = w2[n0 + wn + 16 + col];

#pragma unroll
    for (int mi = 0; mi < 2; ++mi) {
#pragma unroll
        for (int r = 0; r < 4; ++r) {
            float s = tanhf(acc[mi][0][r]) * w2v0 + tanhf(acc[mi][1][r]) * w2v1;
            s += __shfl_xor(s, 1, 64);
            s += __shfl_xor(s, 2, 64);
            s += __shfl_xor(s, 4, 64);
            s += __shfl_xor(s, 8, 64);
            if (col == 0)
                red[wm + mi * 16 + quad * 4 + r][wn >> 5] = s;
        }
    }
    __syncthreads();
    if (t < 64)
        part[blockIdx.y * Mtot + m0 + t] = red[t][0] + red[t][1];
}

// ---------------------------------------------------------------------------
// K2 (fused with broadcast): per batch b:
//   scores[r] = sum_seg part[seg][b*Rr+r]; p = softmax(scores);
//   vchunk[h'] = sum_r p[r] * img[b,r,h0+h']   (h' in 0..63)
//   out[b, s, h0:h0+64] = vchunk  for all s    (nontemporal broadcast)
// grid (16, 12). NSEG = number of part segments (6 bf16 path / 12 f32 path).
// ---------------------------------------------------------------------------
template <int NSEG>
__global__ __launch_bounds__(256) void k2_softmax_bcast(
    const float* __restrict__ part,
    const float* __restrict__ img,
    float* __restrict__ out)
{
    const int b    = blockIdx.x;
    const int t    = threadIdx.x;
    const int lane = t & 63;
    const int wv   = t >> 6;

    __shared__ float p[Rr];
    __shared__ float wred[4];
    __shared__ float a2[4][65];
    __shared__ float vsh[64];

    float s = 0.f;
    if (t < Rr) {
#pragma unroll
        for (int nt = 0; nt < NSEG; ++nt) s += part[nt * Mtot + b * Rr + t];
    }

    // max over 196 scores: wave shuffle reduce, then 4-entry combine
    float m = (t < Rr) ? s : -INFINITY;
#pragma unroll
    for (int off = 1; off < 64; off <<= 1) m = fmaxf(m, __shfl_xor(m, off, 64));
    if (lane == 0) wred[wv] = m;
    __syncthreads();
    const float mx = fmaxf(fmaxf(wred[0], wred[1]), fmaxf(wred[2], wred[3]));

    float e = (t < Rr) ? __expf(s - mx) : 0.f;
    float sum = e;
#pragma unroll
    for (int off = 1; off < 64; off <<= 1) sum += __shfl_xor(sum, off, 64);
    __syncthreads();                 // all mx reads done before wred reuse
    if (lane == 0) wred[wv] = sum;
    __syncthreads();
    const float inv = 1.f / (wred[0] + wred[1] + wred[2] + wred[3]);
    if (t < Rr) p[t] = e * inv;
    __syncthreads();

    // weighted sum over r, split in 4 groups of 49
    const int h0 = blockIdx.y * 64;
    const int rg = t >> 6;
    const float* imgb = img + (size_t)b * Rr * Hh + h0 + (t & 63);
    float acc = 0.f;
#pragma unroll 7
    for (int r = rg * 49; r < rg * 49 + 49; ++r)
        acc = fmaf(p[r], imgb[(size_t)r * Hh], acc);
    a2[rg][t & 63] = acc;
    __syncthreads();
    if (t < 64) vsh[t] = a2[0][t] + a2[1][t] + a2[2][t] + a2[3][t];
    __syncthreads();

    // Broadcast: out[b, s, h0:h0+64] = vsh for every s.
    const int h4 = t & 15;
    const int s0 = t >> 4;
    const f32x4 val = *(const f32x4*)&vsh[h4 * 4];
    f32x4* op = (f32x4*)(out + (size_t)b * Ss * Hh + (size_t)s0 * Hh + h0) + h4;
#pragma unroll 8
    for (int k = 0; k < Ss / 16; ++k) {
        __builtin_nontemporal_store(val, op);
        op += 16 * (Hh / 4);
    }
}

// ---------------------------------------------------------------------------
extern "C" void kernel_launch(void* const* d_in, const int* in_sizes, int n_in,
                              void* d_out, int out_size, void* d_ws, size_t ws_size,
                              hipStream_t stream)
{
    // Input order: text_features, img_features, W_text, b_text, W_img, w_att, b_att
    const float* img   = (const float*)d_in[1];
    const float* W_img = (const float*)d_in[4];
    const float* w_att = (const float*)d_in[5];
    // text_features / W_text / b_text / b_att are mathematically dead:
    // softmax over r is invariant to the per-(b,s) text score and to b_att.

    float* part = (float*)d_ws;                  // <= NT*Mtot floats
    size_t off  = ((size_t)(NT * Mtot + Bb * Hh) * 4 + 15) & ~(size_t)15;
    short* imgbf = (short*)((char*)d_ws + off);                  // 4816896 B
    short* Wbf   = imgbf + (size_t)Mtot * Hh;                    // 1179648 B
    const size_t need = off + ((size_t)Mtot * Hh + (size_t)Hh * Hh) * 2;

    float* out = (float*)d_out;
    const bool usebf = (ws_size >= need);        // constant across calls -> graph-safe

    if (usebf) {
        const int na4 = (Mtot * Hh) / 4;         // 602112
        const int nb4 = (Hh * Hh) / 4;           // 147456
        k0_cvt<<<(na4 + nb4) / 256, 256, 0, stream>>>(
            (const f32x4*)img, (short4v*)imgbf, na4,
            (const f32x4*)W_img, (short4v*)Wbf);
        k1_mfma_bf16<<<dim3(Mtot / 64, NT2), 256, 0, stream>>>(imgbf, Wbf, w_att, part);
        k2_softmax_bcast<NT2><<<dim3(Bb, NT), 256, 0, stream>>>(part, img, out);
    } else {
        k1_mfma_f32<<<dim3(Mtot / 64, NT), 256, 0, stream>>>(img, W_img, w_att, part);
        k2_softmax_bcast<NT><<<dim3(Bb, NT), 256, 0, stream>>>(part, img, out);
    }
}